// Round 7
// baseline (528.705 us; speedup 1.0000x reference)
//
#include <hip/hip_runtime.h>
#include <hip/hip_bf16.h>

// Problem constants (fixed by reference)
#define NN 100000
#define EE 1600000
#define HH 128
#define NB 391      // buckets = ceil(NN/256)
#define CAP 5120    // padded bucket capacity
#define GB 1563     // total 64-row tiles = ceil(NN/64)
#define PT 3        // tiles per persistent gemm block
#define PBK 521     // persistent gemm blocks: 521*3 = 1563 exactly
#define SB 256      // scatter blocks
#define EPB (EE / SB)   // 6250 edges per scatter block (exact)

typedef short bf16x8 __attribute__((ext_vector_type(8)));
typedef short bf16x4 __attribute__((ext_vector_type(4)));
typedef float f32x4  __attribute__((ext_vector_type(4)));

__device__ inline short f2bf(float v) {
    __hip_bfloat16 b = __float2bfloat16(v);
    return *reinterpret_cast<short*>(&b);
}

// direct global->LDS staging (16B per lane, LDS dest = uniform base + lane*16)
typedef __attribute__((address_space(1))) void gvoid_t;
typedef __attribute__((address_space(3))) void svoid_t;
__device__ __forceinline__ void gload16(const void* g, void* l) {
    __builtin_amdgcn_global_load_lds((gvoid_t*)g, (svoid_t*)l, 16, 0, 0);
}

// Compiler-order fence (r2 lesson: asm waitcnt orders the HW, not the compiler)
__device__ __forceinline__ void ld_fence() { asm volatile("" ::: "memory"); }

// counted-vmcnt barrier: wait own outstanding vmem down to N, then raw s_barrier.
template <int N>
__device__ __forceinline__ void wait_vm_bar() {
    if constexpr (N == 0)
        asm volatile("s_waitcnt vmcnt(0)\n\ts_barrier" ::: "memory");
    else if constexpr (N == 2)
        asm volatile("s_waitcnt vmcnt(2)\n\ts_barrier" ::: "memory");
    else if constexpr (N == 4)
        asm volatile("s_waitcnt vmcnt(4)\n\ts_barrier" ::: "memory");
    else if constexpr (N == 8)
        asm volatile("s_waitcnt vmcnt(8)\n\ts_barrier" ::: "memory");
    else if constexpr (N == 10)
        asm volatile("s_waitcnt vmcnt(10)\n\ts_barrier" ::: "memory");
    else if constexpr (N == 12)
        asm volatile("s_waitcnt vmcnt(12)\n\ts_barrier" ::: "memory");
    else
        static_assert(N == 0 || N == 2 || N == 4 || N == 8 || N == 10 || N == 12,
                      "bad N");
}
__device__ __forceinline__ void barrier_only() {
    asm volatile("s_barrier" ::: "memory");
}

// ---------------------------------------------------------------------------
// Launch 1: weight prep (blocks 0..127) + zero bucket cursors (block 128)
// ---------------------------------------------------------------------------
__global__ __launch_bounds__(1024) void prep_kernel(
    const float* __restrict__ Wl0, const float* __restrict__ Wr0,
    const float* __restrict__ Wl1, const float* __restrict__ Wr1,
    const float* __restrict__ Wl2, const float* __restrict__ Wr2,
    __hip_bfloat16* __restrict__ WT0, __hip_bfloat16* __restrict__ WT1,
    __hip_bfloat16* __restrict__ WT2, int* __restrict__ bcur) {
    const int t = threadIdx.x;
    if (blockIdx.x == 128) {
        if (t < NB) bcur[t] = 0;
        return;
    }
    int id = blockIdx.x * 1024 + t;              // 0 .. 131071
    if (id < 65536) {                            // layer 0: K=256
        int k = id & 255, n = id >> 8;
        float v = (n < 128) ? Wl0[(size_t)k * 128 + n]
                            : Wr0[(size_t)k * 128 + (n - 128)];
        WT0[(size_t)n * 256 + k] = __float2bfloat16(v);
    } else {
        id -= 65536;
        int layer = id >> 15;                    // 0 -> L1, 1 -> L2
        int u = id & 32767;
        int k = u & 127, n = u >> 7;
        const float* Wl = layer ? Wl2 : Wl1;
        const float* Wr = layer ? Wr2 : Wr1;
        __hip_bfloat16* WT = layer ? WT2 : WT1;
        float v = (n < 128) ? Wl[(size_t)k * 128 + n]
                            : Wr[(size_t)k * 128 + (n - 128)];
        WT[(size_t)n * 128 + k] = __float2bfloat16(v);
    }
}

// ---------------------------------------------------------------------------
// PERSISTENT MFMA GEMM body, r22: [z | r] = h @ [Wl|Wr].
// r6 diagnosis: the all-upfront burst put ~98 MB in flight device-wide ->
// Little's-law queueing latency ~18us per block generation = the invariant
// ~70us of r0-r6 (per-CU stall 55us; MFMA 4.7us; no scratch traffic).
// Fix: persistent blocks (521 x 3 tiles), weights loaded ONCE, two
// ping-pong 64-K-step stage buffers with ONE-step lookahead (~8KB/wave,
// ~16MB device-wide in flight — continuous steady-state issue), dedicated
// epilogue LDS region (no aliasing, no mid-loop drain). Fully unrolled
// explicit schedule; counted waits derived from the fenced issue order,
// INCLUDING the 8 epilogue stores per tile in the vmcnt arithmetic:
//  L0 (4 steps/tile, stage batch = 4 loads):
//   W[32]F s0 F s1 F w4 | q0..2: w4 C bar s(q+2) F | q3: w4 C bar s5 F epi0
//   q4,5: w12 | q6: w4 | q7: w4 + epi1 | q8,9: w12 | q10: w4 | q11: w0; epi2
//  hidden (2 steps/tile, batch = 2 loads):
//   W[16]F s0 F s1 F w2 | q0: w2 | q1: w2 + epi0 | q2,3: w10 (+epi1) |
//   q4: w10 | q5: w8; epi2
// Epilogue: acc -> dedicated [64][EW] region, lgkm0+bar, coop 16B stores
// (z cols 0-127, r cols 128-255, bias folded). In-place zout==hin safe:
// a block stages only its own rows and all its stage loads of a row retire
// before that row's epilogue store.
// ---------------------------------------------------------------------------
#define EW 264    // epilogue LDS row stride in halves (528 B, 16B-aligned)
template <int K, bool FIRST>
__device__ __forceinline__ void gemm_persist(
    short* __restrict__ lsh,
    const __hip_bfloat16* hin,
    const float* __restrict__ x0, const float* __restrict__ x1,
    const float* __restrict__ x2, const float* __restrict__ x3,
    const __hip_bfloat16* __restrict__ wt, const float* __restrict__ bias,
    __hip_bfloat16* zout, __hip_bfloat16* __restrict__ rout) {
    const int t    = threadIdx.x;
    const int w    = t >> 6;
    const int lane = t & 63;
    const int quad = lane >> 4;
    const int l16  = lane & 15;
    const int g0   = blockIdx.x * PT;            // first tile of this block

    constexpr int SPT  = K / 64;                 // steps per tile: 4 / 2
    constexpr int BUFB = FIRST ? 16384 : 8192;   // LDS bytes per stage buffer
    char*  const lc  = (char*)lsh;
    short* const eph = (short*)(lc + 2 * BUFB);  // dedicated epilogue region

    const __hip_bfloat16* afeat[4];
#pragma unroll
    for (int ft = 0; ft < 4; ++ft)
        afeat[ft] = wt + (size_t)(w * 64 + ft * 16 + l16) * K + quad * 8;

    f32x4 acc[4][4];
#pragma unroll
    for (int ft = 0; ft < 4; ++ft)
#pragma unroll
        for (int nt = 0; nt < 4; ++nt)
            acc[ft][nt] = (f32x4){0.f, 0.f, 0.f, 0.f};

    bf16x8 wreg[SPT][8];   // weights for ALL steps, loaded once per block

    // stage step q (tile g0+q/SPT, 64-k slice q%SPT) into buffer q&1
    auto stage = [&](int q) {
        const int n0 = (g0 + q / SPT) * 64;
        const int p  = q % SPT;
        char* lb = lc + (q & 1) * BUFB;
        if constexpr (FIRST) {
            const float* sp = (p == 0) ? x0 : (p == 1) ? x1 : (p == 2) ? x2 : x3;
#pragma unroll
            for (int i = 0; i < 4; ++i) {
                const int j   = w * 4 + i;           // 1KB chunk = 4 rows
                const int row = j * 4 + (lane >> 4);
                int rg = n0 + row; if (rg > NN - 1) rg = NN - 1;
                const int colb = ((lane & 15) * 16) ^ ((row & 15) << 4);
                gload16((const char*)sp + (size_t)rg * 256 + colb, lb + j * 1024);
            }
        } else {
#pragma unroll
            for (int i = 0; i < 2; ++i) {
                const int j   = w * 2 + i;           // 1KB chunk = 8 rows
                const int row = j * 8 + (lane >> 3);
                int rg = n0 + row; if (rg > NN - 1) rg = NN - 1;
                const int colb = ((lane & 7) * 16) ^ ((row & 7) << 4);
                gload16((const char*)hin + (size_t)rg * 256 + p * 128 + colb,
                        lb + j * 1024);
            }
        }
    };

    // compute step q from buffer q&1 with weights wreg[q%SPT]
    auto compute = [&](int q) {
        const char* lb = lc + (q & 1) * BUFB;
        const int   s  = q % SPT;
#pragma unroll
        for (int kcl = 0; kcl < 2; ++kcl) {
#pragma unroll
            for (int nt = 0; nt < 4; ++nt) {
                const int row = nt * 16 + l16;
                bf16x8 b;
                if constexpr (FIRST) {
                    const int sw = (row & 15) << 4;
                    const int B0 = kcl * 128 + quad * 32;
                    const char* rb = lb + row * 256;
                    const f32x4 lo = *(const f32x4*)(rb + ((B0) ^ sw));
                    const f32x4 hi = *(const f32x4*)(rb + ((B0 + 16) ^ sw));
                    b[0] = f2bf(lo[0]); b[1] = f2bf(lo[1]);
                    b[2] = f2bf(lo[2]); b[3] = f2bf(lo[3]);
                    b[4] = f2bf(hi[0]); b[5] = f2bf(hi[1]);
                    b[6] = f2bf(hi[2]); b[7] = f2bf(hi[3]);
                } else {
                    const int sw = (row & 7) << 4;
                    const int B0 = kcl * 64 + quad * 16;
                    b = *(const bf16x8*)(lb + row * 128 + (B0 ^ sw));
                }
#pragma unroll
                for (int ft = 0; ft < 4; ++ft)
                    acc[ft][nt] = __builtin_amdgcn_mfma_f32_16x16x32_bf16(
                        wreg[s][kcl * 4 + ft], b, acc[ft][nt], 0, 0, 0);
            }
        }
    };

    // epilogue for tile tl: acc -> eph -> global, then reset acc. Adds 8
    // 16B stores to the vmcnt stream (counted in the schedule waits).
    auto epi = [&](int tl) {
        const int n0 = (g0 + tl) * 64;
#pragma unroll
        for (int ft = 0; ft < 4; ++ft) {
            const int fb = ft * 16 + quad * 4;
            float4 bv = make_float4(0.f, 0.f, 0.f, 0.f);
            if (w >= 2) bv = *(const float4*)&bias[(w - 2) * 64 + fb];
            const int cbase = (w & 1) * 64 + ((w >= 2) ? 128 : 0);
#pragma unroll
            for (int nt = 0; nt < 4; ++nt) {
                const f32x4 a = acc[ft][nt];
                bf16x4 p;
                p[0] = f2bf(a[0] + bv.x); p[1] = f2bf(a[1] + bv.y);
                p[2] = f2bf(a[2] + bv.z); p[3] = f2bf(a[3] + bv.w);
                *(bf16x4*)&eph[(nt * 16 + l16) * EW + cbase + fb] = p;
                acc[ft][nt] = (f32x4){0.f, 0.f, 0.f, 0.f};
            }
        }
        asm volatile("s_waitcnt lgkmcnt(0)\n\ts_barrier" ::: "memory");
#pragma unroll
        for (int u = 0; u < 8; ++u) {            // 64 rows x 32 bf16x8-chunks
            const int id  = u * 256 + t;
            const int row = id >> 5, ch = (id & 31) * 8;
            const int nd  = n0 + row;
            if (nd < NN) {
                const bf16x8 v = *(const bf16x8*)&eph[row * EW + ch];
                if (ch < 128) *(bf16x8*)&zout[(size_t)nd * HH + ch] = v;
                else          *(bf16x8*)&rout[(size_t)nd * HH + (ch - 128)] = v;
            }
        }
        ld_fence();
    };

    // weights once (oldest in the vmcnt queue)
#pragma unroll
    for (int p = 0; p < SPT; ++p)
#pragma unroll
        for (int kcl = 0; kcl < 2; ++kcl)
#pragma unroll
            for (int ft = 0; ft < 4; ++ft)
                wreg[p][kcl * 4 + ft] =
                    *(const bf16x8*)(afeat[ft] + (p * 2 + kcl) * 32);
    ld_fence();
    stage(0); ld_fence();
    stage(1); ld_fence();

    if constexpr (FIRST) {                        // 12 steps, batch=4
        wait_vm_bar<4>();  compute(0);  barrier_only(); stage(2);  ld_fence();
        wait_vm_bar<4>();  compute(1);  barrier_only(); stage(3);  ld_fence();
        wait_vm_bar<4>();  compute(2);  barrier_only(); stage(4);  ld_fence();
        wait_vm_bar<4>();  compute(3);  barrier_only(); stage(5);  ld_fence(); epi(0);
        wait_vm_bar<12>(); compute(4);  barrier_only(); stage(6);  ld_fence();
        wait_vm_bar<12>(); compute(5);  barrier_only(); stage(7);  ld_fence();
        wait_vm_bar<4>();  compute(6);  barrier_only(); stage(8);  ld_fence();
        wait_vm_bar<4>();  compute(7);  barrier_only(); stage(9);  ld_fence(); epi(1);
        wait_vm_bar<12>(); compute(8);  barrier_only(); stage(10); ld_fence();
        wait_vm_bar<12>(); compute(9);  barrier_only(); stage(11); ld_fence();
        wait_vm_bar<4>();  compute(10); barrier_only();
        wait_vm_bar<0>();  compute(11);
        epi(2);
    } else {                                      // 6 steps, batch=2
        wait_vm_bar<2>();  compute(0); barrier_only(); stage(2); ld_fence();
        wait_vm_bar<2>();  compute(1); barrier_only(); stage(3); ld_fence(); epi(0);
        wait_vm_bar<10>(); compute(2); barrier_only(); stage(4); ld_fence();
        wait_vm_bar<10>(); compute(3); barrier_only(); stage(5); ld_fence(); epi(1);
        wait_vm_bar<10>(); compute(4); barrier_only();
        wait_vm_bar<8>();  compute(5);
        epi(2);
    }
}

// L0: 2x16KB stage + 33.8KB epilogue = 65KB -> 2 blocks/CU
__global__ __launch_bounds__(256, 2) void gemm0_kernel(
    const float* __restrict__ x0, const float* __restrict__ x1,
    const float* __restrict__ x2, const float* __restrict__ x3,
    const __hip_bfloat16* __restrict__ wt, const float* __restrict__ bias,
    __hip_bfloat16* __restrict__ zout, __hip_bfloat16* __restrict__ rout) {
    __shared__ short lsh[33280];
    gemm_persist<256, true>(lsh, nullptr, x0, x1, x2, x3, wt, bias, zout, rout);
}

// hidden: 2x8KB stage + 33.8KB epilogue = 49KB -> 3 blocks/CU
template <int K>
__global__ __launch_bounds__(256, 2) void gemm_kernel(
    const __hip_bfloat16* hin,
    const __hip_bfloat16* __restrict__ wt, const float* __restrict__ bias,
    __hip_bfloat16* zout, __hip_bfloat16* __restrict__ rout) {
    __shared__ short lsh[25088];
    gemm_persist<K, false>(lsh, hin, nullptr, nullptr, nullptr, nullptr,
                           wt, bias, zout, rout);
}

// ---------------------------------------------------------------------------
// Edge scatter, SB=256 blocks x 6250 edges; 16-deep register-blocked loads.
// ---------------------------------------------------------------------------
__global__ __launch_bounds__(256) void scatter_kernel(
    const int* __restrict__ srcv, const int* __restrict__ dstv,
    int* __restrict__ bcur, int* __restrict__ pairs) {
    __shared__ int hist[NB];
    __shared__ int base[NB];
    const int t = threadIdx.x;

    for (int j = t; j < NB; j += 256) hist[j] = 0;
    __syncthreads();

    const int e0    = blockIdx.x * EPB;
    const int eend_ = e0 + EPB;

    for (int be = e0; be < eend_; be += 4096) {
        int d[16];
#pragma unroll
        for (int u = 0; u < 16; ++u) {
            const int e = be + u * 256 + t;
            d[u] = (e < eend_) ? dstv[e] : -1;
        }
#pragma unroll
        for (int u = 0; u < 16; ++u)
            if (d[u] >= 0) atomicAdd(&hist[d[u] >> 8], 1);
    }
    __syncthreads();

    for (int j = t; j < NB; j += 256)
        base[j] = hist[j] ? atomicAdd(&bcur[j], hist[j]) : 0;
    __syncthreads();
    for (int j = t; j < NB; j += 256) hist[j] = base[j];   // reuse as cursor
    __syncthreads();

    for (int be = e0; be < eend_; be += 4096) {
        int s[16], d[16];
#pragma unroll
        for (int u = 0; u < 16; ++u) {
            const int e = be + u * 256 + t;
            if (e < eend_) { s[u] = srcv[e]; d[u] = dstv[e]; }
            else d[u] = -1;
        }
#pragma unroll
        for (int u = 0; u < 16; ++u)
            if (d[u] >= 0) {
                const int b   = d[u] >> 8;
                const int pos = atomicAdd(&hist[b], 1);
                if (pos < CAP) pairs[b * CAP + pos] = (s[u] << 8) | (d[u] & 255);
            }
    }
}

// ---------------------------------------------------------------------------
// Phase 2: per-bucket counting sort -> csr grouped by node + beg/end/inv.
// ---------------------------------------------------------------------------
__global__ __launch_bounds__(256) void finalize_kernel(
    const int* __restrict__ bcur, const int* __restrict__ pairs,
    int* __restrict__ csr, int* __restrict__ beg, int* __restrict__ eend,
    float* __restrict__ inv) {
    __shared__ int cnt[256];
    __shared__ int scn[256];
    __shared__ int cur[256];
    const int b = blockIdx.x, t = threadIdx.x;
    int m = bcur[b];
    if (m > CAP) m = CAP;

    cnt[t] = 0;
    __syncthreads();
    for (int e = t; e < m; e += 256)
        atomicAdd(&cnt[pairs[b * CAP + e] & 255], 1);
    __syncthreads();

    const int v = cnt[t];
    scn[t] = v;
    __syncthreads();
    for (int st = 1; st < 256; st <<= 1) {
        int tv = (t >= st) ? scn[t - st] : 0;
        __syncthreads();
        scn[t] += tv;
        __syncthreads();
    }
    const int myStart = scn[t] - v;          // exclusive scan
    cur[t] = myStart;
    __syncthreads();

    for (int e = t; e < m; e += 256) {
        const int pk  = pairs[b * CAP + e];
        const int pos = atomicAdd(&cur[pk & 255], 1);
        csr[b * CAP + pos] = pk >> 8;
    }

    const int node = b * 256 + t;
    if (node < NN) {
        beg[node]  = b * CAP + myStart;
        eend[node] = b * CAP + myStart + v;
        inv[node]  = 1.0f / fmaxf((float)v, 1.0f);
    }
}

// ---------------------------------------------------------------------------
// Aggregation + combine: h_out = relu(mean_{in-edges}(z[src]) + r)
// One wave per node; 4 groups x 16 lanes; 16B loads; 4x unroll.
// LAST: fuse layer-3 projection (h3 in f32 regs -> dot Wl3/Wr3 -> z3/r3).
// ---------------------------------------------------------------------------
template <bool LAST>
__global__ __launch_bounds__(256) void aggregate_kernel(
    const __hip_bfloat16* __restrict__ z, __hip_bfloat16* __restrict__ rio,
    const int* __restrict__ beg, const int* __restrict__ eend,
    const int* __restrict__ csr, const float* __restrict__ inv,
    const float* __restrict__ Wl3, const float* __restrict__ Wr3,
    const float* __restrict__ b3, float* __restrict__ z3,
    float* __restrict__ r3) {
    const int i    = (blockIdx.x * 256 + threadIdx.x) >> 6;
    const int lane = threadIdx.x & 63;
    const int g    = lane >> 4;          // edge slot 0..3
    const int l16  = lane & 15;          // 16B chunk within the z row
    if (i >= NN) return;
    const int b0 = beg[i], e0 = eend[i];

    float acc[8];
#pragma unroll
    for (int j = 0; j < 8; ++j) acc[j] = 0.f;

    int e = b0 + g;
    for (; e + 12 < e0; e += 16) {
        const int s0 = csr[e];
        const int s1 = csr[e + 4];
        const int s2 = csr[e + 8];
        const int s3 = csr[e + 12];
        const bf16x8 z0 = *(const bf16x8*)&z[(size_t)s0 * HH + l16 * 8];
        const bf16x8 z1 = *(const bf16x8*)&z[(size_t)s1 * HH + l16 * 8];
        const bf16x8 z2 = *(const bf16x8*)&z[(size_t)s2 * HH + l16 * 8];
        const bf16x8 z3v = *(const bf16x8*)&z[(size_t)s3 * HH + l16 * 8];
        const __hip_bfloat162* p0 = (const __hip_bfloat162*)&z0;
        const __hip_bfloat162* p1 = (const __hip_bfloat162*)&z1;
        const __hip_bfloat162* p2 = (const __hip_bfloat162*)&z2;
        const __hip_bfloat162* p3 = (const __hip_bfloat162*)&z3v;
#pragma unroll
        for (int j = 0; j < 4; ++j) {
            acc[2 * j]     += __bfloat162float(p0[j].x) + __bfloat162float(p1[j].x)
                            + __bfloat162float(p2[j].x) + __bfloat162float(p3[j].x);
            acc[2 * j + 1] += __bfloat162float(p0[j].y) + __bfloat162float(p1[j].y)
                            + __bfloat162float(p2[j].y) + __bfloat162float(p3[j].y);
        }
    }
    for (; e < e0; e += 4) {
        const int s0 = csr[e];
        const bf16x8 z0 = *(const bf16x8*)&z[(size_t)s0 * HH + l16 * 8];
        const __hip_bfloat162* p0 = (const __hip_bfloat162*)&z0;
#pragma unroll
        for (int j = 0; j < 4; ++j) {
            acc[2 * j]     += __bfloat162float(p0[j].x);
            acc[2 * j + 1] += __bfloat162float(p0[j].y);
        }
    }

#pragma unroll
    for (int j = 0; j < 8; ++j) {
        acc[j] += __shfl_xor(acc[j], 16, 64);
        acc[j] += __shfl_xor(acc[j], 32, 64);
    }

    const float iv = inv[i];
    const int   f  = l16 * 8 + g * 2;
    const __hip_bfloat162 rv = *(const __hip_bfloat162*)&rio[(size_t)i * HH + f];
    const float ox = fmaxf(acc[g * 2]     * iv + __bfloat162float(rv.x), 0.f);
    const float oy = fmaxf(acc[g * 2 + 1] * iv + __bfloat162float(rv.y), 0.f);

    if (!LAST) {
        __hip_bfloat162 o;
        o.x = __float2bfloat16(ox);
        o.y = __float2bfloat16(oy);
        *(__hip_bfloat162*)&rio[(size_t)i * HH + f] = o;
    } else {
        const float2 wl = *(const float2*)&Wl3[f];
        const float2 wr = *(const float2*)&Wr3[f];
        float al = ox * wl.x + oy * wl.y;
        float ar = ox * wr.x + oy * wr.y;
#pragma unroll
        for (int m = 32; m; m >>= 1) {
            al += __shfl_xor(al, m, 64);
            ar += __shfl_xor(ar, m, 64);
        }
        if (lane == 0) {
            z3[i] = al;
            r3[i] = ar + b3[0];
        }
    }
}

// Final: out[i] = sigmoid(mean(z3[src]) + r3[i]); per-block partial sums
__global__ __launch_bounds__(256) void final_kernel(
    const float* __restrict__ z3, const float* __restrict__ r3,
    const int* __restrict__ beg, const int* __restrict__ eend,
    const int* __restrict__ csr, const float* __restrict__ inv,
    float* __restrict__ out, float* __restrict__ partial) {
    __shared__ float red[4];
    const int i    = (blockIdx.x * 256 + threadIdx.x) >> 6;
    const int lane = threadIdx.x & 63;
    const int w    = threadIdx.x >> 6;
    float v = 0.f;
    if (i < NN) {
        const int b0 = beg[i], e0 = eend[i];
        float a = 0.f;
        for (int e = b0 + lane; e < e0; e += 64) a += z3[csr[e]];
#pragma unroll
        for (int m = 32; m; m >>= 1) a += __shfl_xor(a, m, 64);
        const float pre = a * inv[i] + r3[i];
        const float s = 1.f / (1.f + __expf(-pre));
        if (lane == 0) { out[i] = s; v = s; }
    }
    if (lane == 0) red[w] = v;
    __syncthreads();
    if (threadIdx.x == 0)
        partial[blockIdx.x] = red[0] + red[1] + red[2] + red[3];
}

__global__ __launch_bounds__(256) void mean_kernel(const float* __restrict__ partial,
                                                   int nb, float* __restrict__ out) {
    __shared__ float lds[256];
    float s = 0.f;
    for (int i = threadIdx.x; i < nb; i += 256) s += partial[i];
    lds[threadIdx.x] = s;
    __syncthreads();
    for (int st = 128; st; st >>= 1) {
        if (threadIdx.x < st) lds[threadIdx.x] += lds[threadIdx.x + st];
        __syncthreads();
    }
    if (threadIdx.x == 0) out[NN] = lds[0] / (float)NN;
}

// ---------------------------------------------------------------------------
extern "C" void kernel_launch(void* const* d_in, const int* in_sizes, int n_in,
                              void* d_out, int out_size, void* d_ws, size_t ws_size,
                              hipStream_t stream) {
    const float* x    = (const float*)d_in[0];
    const float* diff = (const float*)d_in[1];
    const float* rec  = (const float*)d_in[2];
    const float* hid  = (const float*)d_in[3];
    const int* edge   = (const int*)d_in[4];
    const int* esrc = edge;        // row 0
    const int* edst = edge + EE;   // row 1
    const float* Wl0 = (const float*)d_in[5];
    const float* Wr0 = (const float*)d_in[6];
    const float* b0  = (const float*)d_in[7];
    const float* Wl1 = (const float*)d_in[8];
    const float* Wr1 = (const float*)d_in[9];
    const float* b1  = (const float*)d_in[10];
    const float* Wl2 = (const float*)d_in[11];
    const float* Wr2 = (const float*)d_in[12];
    const float* b2  = (const float*)d_in[13];
    const float* Wl3 = (const float*)d_in[14];
    const float* Wr3 = (const float*)d_in[15];
    const float* b3  = (const float*)d_in[16];
    float* out = (float*)d_out;

    // workspace carve-out (256B aligned) — total ~70 MB
    char* w = (char*)d_ws;
    auto alloc = [&](size_t bytes) -> void* {
        void* p = (void*)w;
        w += (bytes + 255) & ~(size_t)255;
        return p;
    };
    __hip_bfloat16* bufA = (__hip_bfloat16*)alloc((size_t)NN * HH * 2);  // 25.6 MB
    __hip_bfloat16* bufB = (__hip_bfloat16*)alloc((size_t)NN * HH * 2);  // 25.6 MB
    __hip_bfloat16* WT0  = (__hip_bfloat16*)alloc((size_t)256 * 256 * 2);
    __hip_bfloat16* WT1  = (__hip_bfloat16*)alloc((size_t)256 * 128 * 2);
    __hip_bfloat16* WT2  = (__hip_bfloat16*)alloc((size_t)256 * 128 * 2);
    int*   pairs   = (int*)alloc((size_t)NB * CAP * 4);                  // 8.0 MB
    int*   csr     = (int*)alloc((size_t)NB * CAP * 4);                  // 8.0 MB
    int*   bcur    = (int*)alloc((size_t)512 * 4);
    int*   beg     = (int*)alloc((size_t)NN * 4);
    int*   eend    = (int*)alloc((size_t)NN * 4);
    float* inv     = (float*)alloc((size_t)NN * 4);
    float* z3      = (float*)alloc((size_t)NN * 4);
    float* r3      = (float*)alloc((size_t)NN * 4);
    float* partial = (float*)alloc((size_t)25000 * 4);

    const int WB = (NN + 3) / 4;             // 25000 (1 node/wave)

    // Launch 1: weight prep + zero cursors (independent, tiny)
    prep_kernel<<<129, 1024, 0, stream>>>(Wl0, Wr0, Wl1, Wr1, Wl2, Wr2,
                                          WT0, WT1, WT2, bcur);

    // Launch 2: edge scatter
    scatter_kernel<<<SB, 256, 0, stream>>>(esrc, edst, bcur, pairs);

    // Launch 3: gemm L0 (z -> A, r -> B), persistent blocks
    gemm0_kernel<<<PBK, 256, 0, stream>>>(x, diff, rec, hid, WT0, b0, bufA, bufB);

    // Launch 4: finalize CSR (needs scatter)
    finalize_kernel<<<NB, 256, 0, stream>>>(bcur, pairs, csr, beg, eend, inv);

    // agg L0: h1 -> B (over r)
    aggregate_kernel<false><<<WB, 256, 0, stream>>>(bufA, bufB, beg, eend, csr, inv,
                                                    nullptr, nullptr, nullptr,
                                                    nullptr, nullptr);

    // L1: h in B; z in-place -> B, r -> A; agg: h2 -> A
    gemm_kernel<128><<<PBK, 256, 0, stream>>>(bufB, WT1, b1, bufB, bufA);
    aggregate_kernel<false><<<WB, 256, 0, stream>>>(bufB, bufA, beg, eend, csr, inv,
                                                    nullptr, nullptr, nullptr,
                                                    nullptr, nullptr);

    // L2: h in A; z in-place -> A, r -> B; agg(LAST): fused proj3 -> z3, r3
    gemm_kernel<128><<<PBK, 256, 0, stream>>>(bufA, WT2, b2, bufA, bufB);
    aggregate_kernel<true><<<WB, 256, 0, stream>>>(bufA, bufB, beg, eend, csr, inv,
                                                   Wl3, Wr3, b3, z3, r3);

    // final: aggregate scalars, sigmoid + mean
    final_kernel<<<WB, 256, 0, stream>>>(z3, r3, beg, eend, csr, inv, out, partial);
    mean_kernel<<<1, 256, 0, stream>>>(partial, WB, out);
}

// Round 8
// 468.123 us; speedup vs baseline: 1.1294x; 1.1294x over previous
//
#include <hip/hip_runtime.h>
#include <hip/hip_bf16.h>

// Problem constants (fixed by reference)
#define NN 100000
#define EE 1600000
#define HH 128
#define NB 391      // buckets = ceil(NN/256)
#define CAP 5120    // padded bucket capacity
#define GB 1563     // gemm tiles = ceil(NN/64)
#define SB 256      // scatter blocks
#define EPB (EE / SB)   // 6250 edges per scatter block (exact)
#define FB 6250     // final blocks: 16 nodes/block (4 waves x 4 nodes)

typedef short bf16x8 __attribute__((ext_vector_type(8)));
typedef short bf16x4 __attribute__((ext_vector_type(4)));
typedef float f32x4  __attribute__((ext_vector_type(4)));

__device__ inline short f2bf(float v) {
    __hip_bfloat16 b = __float2bfloat16(v);
    return *reinterpret_cast<short*>(&b);
}

// direct global->LDS staging (16B per lane, LDS dest = uniform base + lane*16)
typedef __attribute__((address_space(1))) void gvoid_t;
typedef __attribute__((address_space(3))) void svoid_t;
__device__ __forceinline__ void gload16(const void* g, void* l) {
    __builtin_amdgcn_global_load_lds((gvoid_t*)g, (svoid_t*)l, 16, 0, 0);
}

// Compiler-order fence (r2 lesson: asm waitcnt orders the HW, not the compiler)
__device__ __forceinline__ void ld_fence() { asm volatile("" ::: "memory"); }

// counted-vmcnt barrier: wait own outstanding vmem down to N, then raw s_barrier.
template <int N>
__device__ __forceinline__ void wait_vm_bar() {
    if constexpr (N == 0)
        asm volatile("s_waitcnt vmcnt(0)\n\ts_barrier" ::: "memory");
    else if constexpr (N == 8)
        asm volatile("s_waitcnt vmcnt(8)\n\ts_barrier" ::: "memory");
    else if constexpr (N == 12)
        asm volatile("s_waitcnt vmcnt(12)\n\ts_barrier" ::: "memory");
    else if constexpr (N == 16)
        asm volatile("s_waitcnt vmcnt(16)\n\ts_barrier" ::: "memory");
    else if constexpr (N == 18)
        asm volatile("s_waitcnt vmcnt(18)\n\ts_barrier" ::: "memory");
    else if constexpr (N == 20)
        asm volatile("s_waitcnt vmcnt(20)\n\ts_barrier" ::: "memory");
    else
        static_assert(N == 0 || N == 8 || N == 12 || N == 16 || N == 18 || N == 20,
                      "bad N");
}
__device__ __forceinline__ void barrier_only() {
    asm volatile("s_barrier" ::: "memory");
}

// ---------------------------------------------------------------------------
// Launch 1: weight prep (blocks 0..127) + zero bucket cursors (block 128)
// ---------------------------------------------------------------------------
__global__ __launch_bounds__(1024) void prep_kernel(
    const float* __restrict__ Wl0, const float* __restrict__ Wr0,
    const float* __restrict__ Wl1, const float* __restrict__ Wr1,
    const float* __restrict__ Wl2, const float* __restrict__ Wr2,
    __hip_bfloat16* __restrict__ WT0, __hip_bfloat16* __restrict__ WT1,
    __hip_bfloat16* __restrict__ WT2, int* __restrict__ bcur) {
    const int t = threadIdx.x;
    if (blockIdx.x == 128) {
        if (t < NB) bcur[t] = 0;
        return;
    }
    int id = blockIdx.x * 1024 + t;              // 0 .. 131071
    if (id < 65536) {                            // layer 0: K=256
        int k = id & 255, n = id >> 8;
        float v = (n < 128) ? Wl0[(size_t)k * 128 + n]
                            : Wr0[(size_t)k * 128 + (n - 128)];
        WT0[(size_t)n * 256 + k] = __float2bfloat16(v);
    } else {
        id -= 65536;
        int layer = id >> 15;                    // 0 -> L1, 1 -> L2
        int u = id & 32767;
        int k = u & 127, n = u >> 7;
        const float* Wl = layer ? Wl2 : Wl1;
        const float* Wr = layer ? Wr2 : Wr1;
        __hip_bfloat16* WT = layer ? WT2 : WT1;
        float v = (n < 128) ? Wl[(size_t)k * 128 + n]
                            : Wr[(size_t)k * 128 + (n - 128)];
        WT[(size_t)n * 128 + k] = __float2bfloat16(v);
    }
}

// ---------------------------------------------------------------------------
// MFMA GEMM body (r18 — the r5-proven version, VGPR 92, no spill):
// [z | r] = h @ [Wl|Wr], 64-row tile, 4 waves. Weights in registers
// (2-deep ping-pong); L0 3-buffer stage pipeline with counted vmcnt +
// fenced issue order; merged one-pass epilogue. r7 lesson: wreg[4][8]
// (128 VGPR live across tiles) spills to scratch — keep 2-deep.
// ---------------------------------------------------------------------------
#define EW 264    // epilogue LDS row stride in halves (528 B, 16B-aligned)
template <int K, bool FIRST>
__device__ __forceinline__ void gemm_body(
    short* __restrict__ lsh, int bid,
    const __hip_bfloat16* hin,
    const float* __restrict__ x0, const float* __restrict__ x1,
    const float* __restrict__ x2, const float* __restrict__ x3,
    const __hip_bfloat16* __restrict__ wt, const float* __restrict__ bias,
    __hip_bfloat16* zout, __hip_bfloat16* __restrict__ rout) {
    const int t    = threadIdx.x;
    const int w    = t >> 6;
    const int lane = t & 63;
    const int quad = lane >> 4;
    const int l16  = lane & 15;
    const int n0   = bid * 64;

    constexpr int BUFB = FIRST ? 16384 : 8192;   // LDS bytes per stage buffer
    char* const lc = (char*)lsh;

    const __hip_bfloat16* afeat[4];
#pragma unroll
    for (int ft = 0; ft < 4; ++ft)
        afeat[ft] = wt + (size_t)(w * 64 + ft * 16 + l16) * K + quad * 8;

    f32x4 acc[4][4];
#pragma unroll
    for (int ft = 0; ft < 4; ++ft)
#pragma unroll
        for (int nt = 0; nt < 4; ++nt)
            acc[ft][nt] = (f32x4){0.f, 0.f, 0.f, 0.f};

    bf16x8 wreg[2][8];   // [parity][kcl*4+ft]

    auto loadW = [&](int p, int pb) {
#pragma unroll
        for (int kcl = 0; kcl < 2; ++kcl)
#pragma unroll
            for (int ft = 0; ft < 4; ++ft)
                wreg[pb][kcl * 4 + ft] =
                    *(const bf16x8*)(afeat[ft] + (p * 2 + kcl) * 32);
    };

    auto stage = [&](int p, int bb) {
        char* lb = lc + bb * BUFB;
        if constexpr (FIRST) {
            const float* sp = (p == 0) ? x0 : (p == 1) ? x1 : (p == 2) ? x2 : x3;
#pragma unroll
            for (int i = 0; i < 4; ++i) {
                const int j   = w * 4 + i;           // 1KB chunk = 4 rows
                const int row = j * 4 + (lane >> 4);
                int rg = n0 + row; if (rg > NN - 1) rg = NN - 1;
                const int colb = ((lane & 15) * 16) ^ ((row & 15) << 4);
                gload16((const char*)sp + (size_t)rg * 256 + colb, lb + j * 1024);
            }
        } else {
#pragma unroll
            for (int i = 0; i < 2; ++i) {
                const int j   = w * 2 + i;           // 1KB chunk = 8 rows
                const int row = j * 8 + (lane >> 3);
                int rg = n0 + row; if (rg > NN - 1) rg = NN - 1;
                const int colb = ((lane & 7) * 16) ^ ((row & 7) << 4);
                gload16((const char*)hin + (size_t)rg * 256 + p * 128 + colb,
                        lb + j * 1024);
            }
        }
    };

    auto compute = [&](int s, int bb, int pb) {
        const char* lb = lc + bb * BUFB;
#pragma unroll
        for (int kcl = 0; kcl < 2; ++kcl) {
#pragma unroll
            for (int nt = 0; nt < 4; ++nt) {
                const int row = nt * 16 + l16;
                bf16x8 b;
                if constexpr (FIRST) {
                    const int sw = (row & 15) << 4;
                    const int B0 = kcl * 128 + quad * 32;
                    const char* rb = lb + row * 256;
                    const f32x4 lo = *(const f32x4*)(rb + ((B0) ^ sw));
                    const f32x4 hi = *(const f32x4*)(rb + ((B0 + 16) ^ sw));
                    b[0] = f2bf(lo[0]); b[1] = f2bf(lo[1]);
                    b[2] = f2bf(lo[2]); b[3] = f2bf(lo[3]);
                    b[4] = f2bf(hi[0]); b[5] = f2bf(hi[1]);
                    b[6] = f2bf(hi[2]); b[7] = f2bf(hi[3]);
                } else {
                    const int sw = (row & 7) << 4;
                    const int B0 = kcl * 64 + quad * 16;
                    b = *(const bf16x8*)(lb + row * 128 + (B0 ^ sw));
                }
#pragma unroll
                for (int ft = 0; ft < 4; ++ft)
                    acc[ft][nt] = __builtin_amdgcn_mfma_f32_16x16x32_bf16(
                        wreg[pb][kcl * 4 + ft], b, acc[ft][nt], 0, 0, 0);
            }
        }
    };

    if constexpr (FIRST) {                   // NS=4, 3 LDS buffers
        stage(0, 0); ld_fence();
        stage(1, 1); ld_fence();
        loadW(0, 0); ld_fence();
        wait_vm_bar<12>(); loadW(1, 1); stage(2, 2); compute(0, 0, 0); barrier_only();
        wait_vm_bar<20>(); loadW(2, 0); stage(3, 0); compute(1, 1, 1); barrier_only();
        wait_vm_bar<12>(); loadW(3, 1);              compute(2, 2, 0); barrier_only();
        wait_vm_bar<8>();                            compute(3, 0, 1); barrier_only();
    } else {                                  // NS=2, 2 LDS buffers
        stage(0, 0); ld_fence();
        stage(1, 1); ld_fence();
        loadW(0, 0); loadW(1, 1);
        wait_vm_bar<18>(); compute(0, 0, 0); barrier_only();
        wait_vm_bar<16>(); compute(1, 1, 1); barrier_only();
    }

    // merged epilogue: all 4 waves transpose into [64][256] (z | r+bias),
    // one sync, one cooperative store pass.
#pragma unroll
    for (int ft = 0; ft < 4; ++ft) {
        const int fb = ft * 16 + quad * 4;
        float4 bv = make_float4(0.f, 0.f, 0.f, 0.f);
        if (w >= 2) bv = *(const float4*)&bias[(w - 2) * 64 + fb];
        const int cbase = (w & 1) * 64 + ((w >= 2) ? 128 : 0);
#pragma unroll
        for (int nt = 0; nt < 4; ++nt) {
            const f32x4 a = acc[ft][nt];
            bf16x4 p;
            p[0] = f2bf(a[0] + bv.x); p[1] = f2bf(a[1] + bv.y);
            p[2] = f2bf(a[2] + bv.z); p[3] = f2bf(a[3] + bv.w);
            *(bf16x4*)&lsh[(nt * 16 + l16) * EW + cbase + fb] = p;
        }
    }
    __syncthreads();
#pragma unroll
    for (int u = 0; u < 8; ++u) {            // 64 rows x 32 bf16x8-chunks
        const int id  = u * 256 + t;
        const int row = id >> 5, ch = (id & 31) * 8;
        const int nd  = n0 + row;
        if (nd < NN) {
            const bf16x8 v = *(const bf16x8*)&lsh[row * EW + ch];
            if (ch < 128) *(bf16x8*)&zout[(size_t)nd * HH + ch] = v;
            else          *(bf16x8*)&rout[(size_t)nd * HH + (ch - 128)] = v;
        }
    }
}

// hidden gemm (layers 1,2): LDS = max(2x8KB dbuf, 64x264x2 epilogue)
template <int K>
__global__ __launch_bounds__(256) void gemm_kernel(
    const __hip_bfloat16* hin,
    const __hip_bfloat16* __restrict__ wt, const float* __restrict__ bias,
    __hip_bfloat16* zout, __hip_bfloat16* __restrict__ rout) {
    __shared__ short lsh[16896];
    gemm_body<K, false>(lsh, blockIdx.x, hin, nullptr, nullptr, nullptr, nullptr,
                        wt, bias, zout, rout);
}

// ---------------------------------------------------------------------------
// Launch 2: standalone edge scatter, SB=256 blocks x 6250 edges.
// 16-deep register-blocked loads both passes (MLP). Pass 1: dst histogram.
// Reservation: one global atomic per touched bucket. Pass 2: re-read
// (L2-hot), place packed (src<<8)|dstLow in reserved ranges.
// ---------------------------------------------------------------------------
__global__ __launch_bounds__(256) void scatter_kernel(
    const int* __restrict__ srcv, const int* __restrict__ dstv,
    int* __restrict__ bcur, int* __restrict__ pairs) {
    __shared__ int hist[NB];
    __shared__ int base[NB];
    const int t = threadIdx.x;

    for (int j = t; j < NB; j += 256) hist[j] = 0;
    __syncthreads();

    const int e0    = blockIdx.x * EPB;
    const int eend_ = e0 + EPB;

    for (int be = e0; be < eend_; be += 4096) {
        int d[16];
#pragma unroll
        for (int u = 0; u < 16; ++u) {
            const int e = be + u * 256 + t;
            d[u] = (e < eend_) ? dstv[e] : -1;
        }
#pragma unroll
        for (int u = 0; u < 16; ++u)
            if (d[u] >= 0) atomicAdd(&hist[d[u] >> 8], 1);
    }
    __syncthreads();

    for (int j = t; j < NB; j += 256)
        base[j] = hist[j] ? atomicAdd(&bcur[j], hist[j]) : 0;
    __syncthreads();
    for (int j = t; j < NB; j += 256) hist[j] = base[j];   // reuse as cursor
    __syncthreads();

    for (int be = e0; be < eend_; be += 4096) {
        int s[16], d[16];
#pragma unroll
        for (int u = 0; u < 16; ++u) {
            const int e = be + u * 256 + t;
            if (e < eend_) { s[u] = srcv[e]; d[u] = dstv[e]; }
            else d[u] = -1;
        }
#pragma unroll
        for (int u = 0; u < 16; ++u)
            if (d[u] >= 0) {
                const int b   = d[u] >> 8;
                const int pos = atomicAdd(&hist[b], 1);
                if (pos < CAP) pairs[b * CAP + pos] = (s[u] << 8) | (d[u] & 255);
            }
    }
}

// ---------------------------------------------------------------------------
// Launch 3 (r8): FINALIZE (blocks [0,NB)) fused with GEMM L0 (blocks
// [NB, NB+GB)). Both depend only on prior launches (finalize: scatter;
// gemm0: prep) — no intra-launch dependency. On a single stream, fusion is
// the only overlap tool; this hides finalize's ~25-40us under gemm0's ~70us
// (r5 hid scatter instead and exposed finalize; scatter is the cheaper one
// to expose). Finalize: per-bucket counting sort -> csr + beg/end/inv.
// ---------------------------------------------------------------------------
__global__ __launch_bounds__(256) void fin_gemm0_kernel(
    const float* __restrict__ x0, const float* __restrict__ x1,
    const float* __restrict__ x2, const float* __restrict__ x3,
    const __hip_bfloat16* __restrict__ wt, const float* __restrict__ bias,
    __hip_bfloat16* __restrict__ zout, __hip_bfloat16* __restrict__ rout,
    const int* __restrict__ bcur, const int* __restrict__ pairs,
    int* __restrict__ csr, int* __restrict__ beg, int* __restrict__ eend,
    float* __restrict__ inv) {
    __shared__ short lsh[24576];            // gemm: 3x16KB; finalize aliases 3KB
    const int t = threadIdx.x;

    if (blockIdx.x >= NB) {
        gemm_body<256, true>(lsh, blockIdx.x - NB, nullptr, x0, x1, x2, x3,
                             wt, bias, zout, rout);
        return;
    }

    int* cnt = (int*)lsh;
    int* scn = cnt + 256;
    int* cur = scn + 256;
    const int b = blockIdx.x;
    int m = bcur[b];
    if (m > CAP) m = CAP;

    cnt[t] = 0;
    __syncthreads();
    for (int e = t; e < m; e += 256)
        atomicAdd(&cnt[pairs[b * CAP + e] & 255], 1);
    __syncthreads();

    const int v = cnt[t];
    scn[t] = v;
    __syncthreads();
    for (int st = 1; st < 256; st <<= 1) {
        int tv = (t >= st) ? scn[t - st] : 0;
        __syncthreads();
        scn[t] += tv;
        __syncthreads();
    }
    const int myStart = scn[t] - v;          // exclusive scan
    cur[t] = myStart;
    __syncthreads();

    for (int e = t; e < m; e += 256) {
        const int pk  = pairs[b * CAP + e];
        const int pos = atomicAdd(&cur[pk & 255], 1);
        csr[b * CAP + pos] = pk >> 8;
    }

    const int node = b * 256 + t;
    if (node < NN) {
        beg[node]  = b * CAP + myStart;
        eend[node] = b * CAP + myStart + v;
        inv[node]  = 1.0f / fmaxf((float)v, 1.0f);
    }
}

// ---------------------------------------------------------------------------
// Aggregation + combine: h_out = relu(mean_{in-edges}(z[src]) + r)
// One wave per node; 4 groups x 16 lanes; 16B loads; 4x unroll.
// LAST: fuse layer-3 projection (h3 in f32 regs -> dot Wl3/Wr3 -> z3/r3).
// ---------------------------------------------------------------------------
template <bool LAST>
__global__ __launch_bounds__(256) void aggregate_kernel(
    const __hip_bfloat16* __restrict__ z, __hip_bfloat16* __restrict__ rio,
    const int* __restrict__ beg, const int* __restrict__ eend,
    const int* __restrict__ csr, const float* __restrict__ inv,
    const float* __restrict__ Wl3, const float* __restrict__ Wr3,
    const float* __restrict__ b3, float* __restrict__ z3,
    float* __restrict__ r3) {
    const int i    = (blockIdx.x * 256 + threadIdx.x) >> 6;
    const int lane = threadIdx.x & 63;
    const int g    = lane >> 4;          // edge slot 0..3
    const int l16  = lane & 15;          // 16B chunk within the z row
    if (i >= NN) return;
    const int b0 = beg[i], e0 = eend[i];

    float acc[8];
#pragma unroll
    for (int j = 0; j < 8; ++j) acc[j] = 0.f;

    int e = b0 + g;
    for (; e + 12 < e0; e += 16) {
        const int s0 = csr[e];
        const int s1 = csr[e + 4];
        const int s2 = csr[e + 8];
        const int s3 = csr[e + 12];
        const bf16x8 z0 = *(const bf16x8*)&z[(size_t)s0 * HH + l16 * 8];
        const bf16x8 z1 = *(const bf16x8*)&z[(size_t)s1 * HH + l16 * 8];
        const bf16x8 z2 = *(const bf16x8*)&z[(size_t)s2 * HH + l16 * 8];
        const bf16x8 z3v = *(const bf16x8*)&z[(size_t)s3 * HH + l16 * 8];
        const __hip_bfloat162* p0 = (const __hip_bfloat162*)&z0;
        const __hip_bfloat162* p1 = (const __hip_bfloat162*)&z1;
        const __hip_bfloat162* p2 = (const __hip_bfloat162*)&z2;
        const __hip_bfloat162* p3 = (const __hip_bfloat162*)&z3v;
#pragma unroll
        for (int j = 0; j < 4; ++j) {
            acc[2 * j]     += __bfloat162float(p0[j].x) + __bfloat162float(p1[j].x)
                            + __bfloat162float(p2[j].x) + __bfloat162float(p3[j].x);
            acc[2 * j + 1] += __bfloat162float(p0[j].y) + __bfloat162float(p1[j].y)
                            + __bfloat162float(p2[j].y) + __bfloat162float(p3[j].y);
        }
    }
    for (; e < e0; e += 4) {
        const int s0 = csr[e];
        const bf16x8 z0 = *(const bf16x8*)&z[(size_t)s0 * HH + l16 * 8];
        const __hip_bfloat162* p0 = (const __hip_bfloat162*)&z0;
#pragma unroll
        for (int j = 0; j < 4; ++j) {
            acc[2 * j]     += __bfloat162float(p0[j].x);
            acc[2 * j + 1] += __bfloat162float(p0[j].y);
        }
    }

#pragma unroll
    for (int j = 0; j < 8; ++j) {
        acc[j] += __shfl_xor(acc[j], 16, 64);
        acc[j] += __shfl_xor(acc[j], 32, 64);
    }

    const float iv = inv[i];
    const int   f  = l16 * 8 + g * 2;
    const __hip_bfloat162 rv = *(const __hip_bfloat162*)&rio[(size_t)i * HH + f];
    const float ox = fmaxf(acc[g * 2]     * iv + __bfloat162float(rv.x), 0.f);
    const float oy = fmaxf(acc[g * 2 + 1] * iv + __bfloat162float(rv.y), 0.f);

    if (!LAST) {
        __hip_bfloat162 o;
        o.x = __float2bfloat16(ox);
        o.y = __float2bfloat16(oy);
        *(__hip_bfloat162*)&rio[(size_t)i * HH + f] = o;
    } else {
        const float2 wl = *(const float2*)&Wl3[f];
        const float2 wr = *(const float2*)&Wr3[f];
        float al = ox * wl.x + oy * wl.y;
        float ar = ox * wr.x + oy * wr.y;
#pragma unroll
        for (int m = 32; m; m >>= 1) {
            al += __shfl_xor(al, m, 64);
            ar += __shfl_xor(ar, m, 64);
        }
        if (lane == 0) {
            z3[i] = al;
            r3[i] = ar + b3[0];
        }
    }
}

// Final (r8): 4 nodes per wave, 16 lanes each (old: 1 node/wave left 48-75%
// of lanes idle for the ~16-element scalar gathers). 16 nodes/block.
__global__ __launch_bounds__(256) void final_kernel(
    const float* __restrict__ z3, const float* __restrict__ r3,
    const int* __restrict__ beg, const int* __restrict__ eend,
    const int* __restrict__ csr, const float* __restrict__ inv,
    float* __restrict__ out, float* __restrict__ partial) {
    __shared__ float red[4];
    const int wv   = (blockIdx.x * 256 + threadIdx.x) >> 6;  // global wave id
    const int lane = threadIdx.x & 63;
    const int sub  = lane >> 4;          // node sub-slot 0..3
    const int l16  = lane & 15;
    const int w    = threadIdx.x >> 6;
    const int i    = wv * 4 + sub;
    float s = 0.f;
    if (i < NN) {
        const int b0 = beg[i], e0 = eend[i];
        float a = 0.f;
        for (int e = b0 + l16; e < e0; e += 16) a += z3[csr[e]];
        a += __shfl_xor(a, 1, 64);
        a += __shfl_xor(a, 2, 64);
        a += __shfl_xor(a, 4, 64);
        a += __shfl_xor(a, 8, 64);
        const float pre = a * inv[i] + r3[i];
        const float sg  = 1.f / (1.f + __expf(-pre));
        if (l16 == 0) { out[i] = sg; s = sg; }
    }
    // sum the 4 group-leader values (lanes 0,16,32,48) across the wave
    s += __shfl_xor(s, 16, 64);
    s += __shfl_xor(s, 32, 64);
    if (lane == 0) red[w] = s;
    __syncthreads();
    if (threadIdx.x == 0)
        partial[blockIdx.x] = red[0] + red[1] + red[2] + red[3];
}

__global__ __launch_bounds__(256) void mean_kernel(const float* __restrict__ partial,
                                                   int nb, float* __restrict__ out) {
    __shared__ float lds[256];
    float s = 0.f;
    for (int i = threadIdx.x; i < nb; i += 256) s += partial[i];
    lds[threadIdx.x] = s;
    __syncthreads();
    for (int st = 128; st; st >>= 1) {
        if (threadIdx.x < st) lds[threadIdx.x] += lds[threadIdx.x + st];
        __syncthreads();
    }
    if (threadIdx.x == 0) out[NN] = lds[0] / (float)NN;
}

// ---------------------------------------------------------------------------
extern "C" void kernel_launch(void* const* d_in, const int* in_sizes, int n_in,
                              void* d_out, int out_size, void* d_ws, size_t ws_size,
                              hipStream_t stream) {
    const float* x    = (const float*)d_in[0];
    const float* diff = (const float*)d_in[1];
    const float* rec  = (const float*)d_in[2];
    const float* hid  = (const float*)d_in[3];
    const int* edge   = (const int*)d_in[4];
    const int* esrc = edge;        // row 0
    const int* edst = edge + EE;   // row 1
    const float* Wl0 = (const float*)d_in[5];
    const float* Wr0 = (const float*)d_in[6];
    const float* b0  = (const float*)d_in[7];
    const float* Wl1 = (const float*)d_in[8];
    const float* Wr1 = (const float*)d_in[9];
    const float* b1  = (const float*)d_in[10];
    const float* Wl2 = (const float*)d_in[11];
    const float* Wr2 = (const float*)d_in[12];
    const float* b2  = (const float*)d_in[13];
    const float* Wl3 = (const float*)d_in[14];
    const float* Wr3 = (const float*)d_in[15];
    const float* b3  = (const float*)d_in[16];
    float* out = (float*)d_out;

    // workspace carve-out (256B aligned) — total ~70 MB
    char* w = (char*)d_ws;
    auto alloc = [&](size_t bytes) -> void* {
        void* p = (void*)w;
        w += (bytes + 255) & ~(size_t)255;
        return p;
    };
    __hip_bfloat16* bufA = (__hip_bfloat16*)alloc((size_t)NN * HH * 2);  // 25.6 MB
    __hip_bfloat16* bufB = (__hip_bfloat16*)alloc((size_t)NN * HH * 2);  // 25.6 MB
    __hip_bfloat16* WT0  = (__hip_bfloat16*)alloc((size_t)256 * 256 * 2);
    __hip_bfloat16* WT1  = (__hip_bfloat16*)alloc((size_t)256 * 128 * 2);
    __hip_bfloat16* WT2  = (__hip_bfloat16*)alloc((size_t)256 * 128 * 2);
    int*   pairs   = (int*)alloc((size_t)NB * CAP * 4);                  // 8.0 MB
    int*   csr     = (int*)alloc((size_t)NB * CAP * 4);                  // 8.0 MB
    int*   bcur    = (int*)alloc((size_t)512 * 4);
    int*   beg     = (int*)alloc((size_t)NN * 4);
    int*   eend    = (int*)alloc((size_t)NN * 4);
    float* inv     = (float*)alloc((size_t)NN * 4);
    float* z3      = (float*)alloc((size_t)NN * 4);
    float* r3      = (float*)alloc((size_t)NN * 4);
    float* partial = (float*)alloc((size_t)25000 * 4);

    const int WB = (NN + 3) / 4;             // 25000 (1 node/wave)

    // Launch 1: weight prep + zero cursors
    prep_kernel<<<129, 1024, 0, stream>>>(Wl0, Wr0, Wl1, Wr1, Wl2, Wr2,
                                          WT0, WT1, WT2, bcur);

    // Launch 2: edge scatter (standalone)
    scatter_kernel<<<SB, 256, 0, stream>>>(esrc, edst, bcur, pairs);

    // Launch 3: finalize CSR (blocks 0..NB) fused with gemm L0 (z->A, r->B)
    fin_gemm0_kernel<<<NB + GB, 256, 0, stream>>>(
        x, diff, rec, hid, WT0, b0, bufA, bufB,
        bcur, pairs, csr, beg, eend, inv);

    // agg L0: h1 -> B (over r)
    aggregate_kernel<false><<<WB, 256, 0, stream>>>(bufA, bufB, beg, eend, csr, inv,
                                                    nullptr, nullptr, nullptr,
                                                    nullptr, nullptr);

    // L1: h in B; z in-place -> B, r -> A; agg: h2 -> A
    gemm_kernel<128><<<GB, 256, 0, stream>>>(bufB, WT1, b1, bufB, bufA);
    aggregate_kernel<false><<<WB, 256, 0, stream>>>(bufB, bufA, beg, eend, csr, inv,
                                                    nullptr, nullptr, nullptr,
                                                    nullptr, nullptr);

    // L2: h in A; z in-place -> A, r -> B; agg(LAST): fused proj3 -> z3, r3
    gemm_kernel<128><<<GB, 256, 0, stream>>>(bufA, WT2, b2, bufA, bufB);
    aggregate_kernel<true><<<WB, 256, 0, stream>>>(bufA, bufB, beg, eend, csr, inv,
                                                   Wl3, Wr3, b3, z3, r3);

    // final: 16 nodes/block, sigmoid + partial sums; then mean
    final_kernel<<<FB, 256, 0, stream>>>(z3, r3, beg, eend, csr, inv, out, partial);
    mean_kernel<<<1, 256, 0, stream>>>(partial, FB, out);
}

// Round 9
// 454.155 us; speedup vs baseline: 1.1641x; 1.0308x over previous
//
#include <hip/hip_runtime.h>
#include <hip/hip_bf16.h>

// Problem constants (fixed by reference)
#define NN 100000
#define EE 1600000
#define HH 128
#define NB 391      // buckets = ceil(NN/256)
#define CAP 5120    // padded bucket capacity
#define GB 1563     // gemm tiles = ceil(NN/64)
#define SB 256      // scatter blocks
#define EPB (EE / SB)   // 6250 edges per scatter block (exact)
#define FB 6250     // final blocks: 16 nodes/block (4 waves x 4 nodes)
#define AB 6250     // aggregate blocks (r9): 16 nodes/block (4 waves x 4 nodes)

typedef short bf16x8 __attribute__((ext_vector_type(8)));
typedef short bf16x4 __attribute__((ext_vector_type(4)));
typedef float f32x4  __attribute__((ext_vector_type(4)));

__device__ inline short f2bf(float v) {
    __hip_bfloat16 b = __float2bfloat16(v);
    return *reinterpret_cast<short*>(&b);
}
__device__ inline float bf2f(short s) {
    unsigned int u = ((unsigned int)(unsigned short)s) << 16;
    return *reinterpret_cast<float*>(&u);
}

// direct global->LDS staging (16B per lane, LDS dest = uniform base + lane*16)
typedef __attribute__((address_space(1))) void gvoid_t;
typedef __attribute__((address_space(3))) void svoid_t;
__device__ __forceinline__ void gload16(const void* g, void* l) {
    __builtin_amdgcn_global_load_lds((gvoid_t*)g, (svoid_t*)l, 16, 0, 0);
}

// Compiler-order fence (r2 lesson: asm waitcnt orders the HW, not the compiler)
__device__ __forceinline__ void ld_fence() { asm volatile("" ::: "memory"); }

// counted-vmcnt barrier: wait own outstanding vmem down to N, then raw s_barrier.
template <int N>
__device__ __forceinline__ void wait_vm_bar() {
    if constexpr (N == 0)
        asm volatile("s_waitcnt vmcnt(0)\n\ts_barrier" ::: "memory");
    else if constexpr (N == 8)
        asm volatile("s_waitcnt vmcnt(8)\n\ts_barrier" ::: "memory");
    else if constexpr (N == 12)
        asm volatile("s_waitcnt vmcnt(12)\n\ts_barrier" ::: "memory");
    else if constexpr (N == 16)
        asm volatile("s_waitcnt vmcnt(16)\n\ts_barrier" ::: "memory");
    else if constexpr (N == 18)
        asm volatile("s_waitcnt vmcnt(18)\n\ts_barrier" ::: "memory");
    else if constexpr (N == 20)
        asm volatile("s_waitcnt vmcnt(20)\n\ts_barrier" ::: "memory");
    else
        static_assert(N == 0 || N == 8 || N == 12 || N == 16 || N == 18 || N == 20,
                      "bad N");
}
__device__ __forceinline__ void barrier_only() {
    asm volatile("s_barrier" ::: "memory");
}

// ---------------------------------------------------------------------------
// Launch 1: weight prep (blocks 0..127) + zero bucket cursors (block 128)
// ---------------------------------------------------------------------------
__global__ __launch_bounds__(1024) void prep_kernel(
    const float* __restrict__ Wl0, const float* __restrict__ Wr0,
    const float* __restrict__ Wl1, const float* __restrict__ Wr1,
    const float* __restrict__ Wl2, const float* __restrict__ Wr2,
    __hip_bfloat16* __restrict__ WT0, __hip_bfloat16* __restrict__ WT1,
    __hip_bfloat16* __restrict__ WT2, int* __restrict__ bcur) {
    const int t = threadIdx.x;
    if (blockIdx.x == 128) {
        if (t < NB) bcur[t] = 0;
        return;
    }
    int id = blockIdx.x * 1024 + t;              // 0 .. 131071
    if (id < 65536) {                            // layer 0: K=256
        int k = id & 255, n = id >> 8;
        float v = (n < 128) ? Wl0[(size_t)k * 128 + n]
                            : Wr0[(size_t)k * 128 + (n - 128)];
        WT0[(size_t)n * 256 + k] = __float2bfloat16(v);
    } else {
        id -= 65536;
        int layer = id >> 15;                    // 0 -> L1, 1 -> L2
        int u = id & 32767;
        int k = u & 127, n = u >> 7;
        const float* Wl = layer ? Wl2 : Wl1;
        const float* Wr = layer ? Wr2 : Wr1;
        __hip_bfloat16* WT = layer ? WT2 : WT1;
        float v = (n < 128) ? Wl[(size_t)k * 128 + n]
                            : Wr[(size_t)k * 128 + (n - 128)];
        WT[(size_t)n * 128 + k] = __float2bfloat16(v);
    }
}

// ---------------------------------------------------------------------------
// MFMA GEMM body (r18 — r5/r8-proven, VGPR 92, no spill): [z|r] = h @ [Wl|Wr],
// 64-row tile, 4 waves. Weights in 2-deep register ping-pong; L0 3-buffer
// stage pipeline with counted vmcnt + fenced issue order; merged epilogue.
// ---------------------------------------------------------------------------
#define EW 264    // epilogue LDS row stride in halves (528 B, 16B-aligned)
template <int K, bool FIRST>
__device__ __forceinline__ void gemm_body(
    short* __restrict__ lsh, int bid,
    const __hip_bfloat16* hin,
    const float* __restrict__ x0, const float* __restrict__ x1,
    const float* __restrict__ x2, const float* __restrict__ x3,
    const __hip_bfloat16* __restrict__ wt, const float* __restrict__ bias,
    __hip_bfloat16* zout, __hip_bfloat16* __restrict__ rout) {
    const int t    = threadIdx.x;
    const int w    = t >> 6;
    const int lane = t & 63;
    const int quad = lane >> 4;
    const int l16  = lane & 15;
    const int n0   = bid * 64;

    constexpr int BUFB = FIRST ? 16384 : 8192;   // LDS bytes per stage buffer
    char* const lc = (char*)lsh;

    const __hip_bfloat16* afeat[4];
#pragma unroll
    for (int ft = 0; ft < 4; ++ft)
        afeat[ft] = wt + (size_t)(w * 64 + ft * 16 + l16) * K + quad * 8;

    f32x4 acc[4][4];
#pragma unroll
    for (int ft = 0; ft < 4; ++ft)
#pragma unroll
        for (int nt = 0; nt < 4; ++nt)
            acc[ft][nt] = (f32x4){0.f, 0.f, 0.f, 0.f};

    bf16x8 wreg[2][8];   // [parity][kcl*4+ft]

    auto loadW = [&](int p, int pb) {
#pragma unroll
        for (int kcl = 0; kcl < 2; ++kcl)
#pragma unroll
            for (int ft = 0; ft < 4; ++ft)
                wreg[pb][kcl * 4 + ft] =
                    *(const bf16x8*)(afeat[ft] + (p * 2 + kcl) * 32);
    };

    auto stage = [&](int p, int bb) {
        char* lb = lc + bb * BUFB;
        if constexpr (FIRST) {
            const float* sp = (p == 0) ? x0 : (p == 1) ? x1 : (p == 2) ? x2 : x3;
#pragma unroll
            for (int i = 0; i < 4; ++i) {
                const int j   = w * 4 + i;           // 1KB chunk = 4 rows
                const int row = j * 4 + (lane >> 4);
                int rg = n0 + row; if (rg > NN - 1) rg = NN - 1;
                const int colb = ((lane & 15) * 16) ^ ((row & 15) << 4);
                gload16((const char*)sp + (size_t)rg * 256 + colb, lb + j * 1024);
            }
        } else {
#pragma unroll
            for (int i = 0; i < 2; ++i) {
                const int j   = w * 2 + i;           // 1KB chunk = 8 rows
                const int row = j * 8 + (lane >> 3);
                int rg = n0 + row; if (rg > NN - 1) rg = NN - 1;
                const int colb = ((lane & 7) * 16) ^ ((row & 7) << 4);
                gload16((const char*)hin + (size_t)rg * 256 + p * 128 + colb,
                        lb + j * 1024);
            }
        }
    };

    auto compute = [&](int s, int bb, int pb) {
        const char* lb = lc + bb * BUFB;
#pragma unroll
        for (int kcl = 0; kcl < 2; ++kcl) {
#pragma unroll
            for (int nt = 0; nt < 4; ++nt) {
                const int row = nt * 16 + l16;
                bf16x8 b;
                if constexpr (FIRST) {
                    const int sw = (row & 15) << 4;
                    const int B0 = kcl * 128 + quad * 32;
                    const char* rb = lb + row * 256;
                    const f32x4 lo = *(const f32x4*)(rb + ((B0) ^ sw));
                    const f32x4 hi = *(const f32x4*)(rb + ((B0 + 16) ^ sw));
                    b[0] = f2bf(lo[0]); b[1] = f2bf(lo[1]);
                    b[2] = f2bf(lo[2]); b[3] = f2bf(lo[3]);
                    b[4] = f2bf(hi[0]); b[5] = f2bf(hi[1]);
                    b[6] = f2bf(hi[2]); b[7] = f2bf(hi[3]);
                } else {
                    const int sw = (row & 7) << 4;
                    const int B0 = kcl * 64 + quad * 16;
                    b = *(const bf16x8*)(lb + row * 128 + (B0 ^ sw));
                }
#pragma unroll
                for (int ft = 0; ft < 4; ++ft)
                    acc[ft][nt] = __builtin_amdgcn_mfma_f32_16x16x32_bf16(
                        wreg[pb][kcl * 4 + ft], b, acc[ft][nt], 0, 0, 0);
            }
        }
    };

    if constexpr (FIRST) {                   // NS=4, 3 LDS buffers
        stage(0, 0); ld_fence();
        stage(1, 1); ld_fence();
        loadW(0, 0); ld_fence();
        wait_vm_bar<12>(); loadW(1, 1); stage(2, 2); compute(0, 0, 0); barrier_only();
        wait_vm_bar<20>(); loadW(2, 0); stage(3, 0); compute(1, 1, 1); barrier_only();
        wait_vm_bar<12>(); loadW(3, 1);              compute(2, 2, 0); barrier_only();
        wait_vm_bar<8>();                            compute(3, 0, 1); barrier_only();
    } else {                                  // NS=2, 2 LDS buffers
        stage(0, 0); ld_fence();
        stage(1, 1); ld_fence();
        loadW(0, 0); loadW(1, 1);
        wait_vm_bar<18>(); compute(0, 0, 0); barrier_only();
        wait_vm_bar<16>(); compute(1, 1, 1); barrier_only();
    }

    // merged epilogue: all 4 waves transpose into [64][256] (z | r+bias),
    // one sync, one cooperative store pass.
#pragma unroll
    for (int ft = 0; ft < 4; ++ft) {
        const int fb = ft * 16 + quad * 4;
        float4 bv = make_float4(0.f, 0.f, 0.f, 0.f);
        if (w >= 2) bv = *(const float4*)&bias[(w - 2) * 64 + fb];
        const int cbase = (w & 1) * 64 + ((w >= 2) ? 128 : 0);
#pragma unroll
        for (int nt = 0; nt < 4; ++nt) {
            const f32x4 a = acc[ft][nt];
            bf16x4 p;
            p[0] = f2bf(a[0] + bv.x); p[1] = f2bf(a[1] + bv.y);
            p[2] = f2bf(a[2] + bv.z); p[3] = f2bf(a[3] + bv.w);
            *(bf16x4*)&lsh[(nt * 16 + l16) * EW + cbase + fb] = p;
        }
    }
    __syncthreads();
#pragma unroll
    for (int u = 0; u < 8; ++u) {            // 64 rows x 32 bf16x8-chunks
        const int id  = u * 256 + t;
        const int row = id >> 5, ch = (id & 31) * 8;
        const int nd  = n0 + row;
        if (nd < NN) {
            const bf16x8 v = *(const bf16x8*)&lsh[row * EW + ch];
            if (ch < 128) *(bf16x8*)&zout[(size_t)nd * HH + ch] = v;
            else          *(bf16x8*)&rout[(size_t)nd * HH + (ch - 128)] = v;
        }
    }
}

// hidden gemm (layers 1,2): LDS = max(2x8KB dbuf, 64x264x2 epilogue)
template <int K>
__global__ __launch_bounds__(256) void gemm_kernel(
    const __hip_bfloat16* hin,
    const __hip_bfloat16* __restrict__ wt, const float* __restrict__ bias,
    __hip_bfloat16* zout, __hip_bfloat16* __restrict__ rout) {
    __shared__ short lsh[16896];
    gemm_body<K, false>(lsh, blockIdx.x, hin, nullptr, nullptr, nullptr, nullptr,
                        wt, bias, zout, rout);
}

// ---------------------------------------------------------------------------
// Launch 2: standalone edge scatter, SB=256 blocks x 6250 edges.
// 16-deep register-blocked loads both passes. Pass 1: dst histogram.
// Reservation: one global atomic per touched bucket. Pass 2: re-read
// (L2-hot), place packed (src<<8)|dstLow in reserved ranges.
// ---------------------------------------------------------------------------
__global__ __launch_bounds__(256) void scatter_kernel(
    const int* __restrict__ srcv, const int* __restrict__ dstv,
    int* __restrict__ bcur, int* __restrict__ pairs) {
    __shared__ int hist[NB];
    __shared__ int base[NB];
    const int t = threadIdx.x;

    for (int j = t; j < NB; j += 256) hist[j] = 0;
    __syncthreads();

    const int e0    = blockIdx.x * EPB;
    const int eend_ = e0 + EPB;

    for (int be = e0; be < eend_; be += 4096) {
        int d[16];
#pragma unroll
        for (int u = 0; u < 16; ++u) {
            const int e = be + u * 256 + t;
            d[u] = (e < eend_) ? dstv[e] : -1;
        }
#pragma unroll
        for (int u = 0; u < 16; ++u)
            if (d[u] >= 0) atomicAdd(&hist[d[u] >> 8], 1);
    }
    __syncthreads();

    for (int j = t; j < NB; j += 256)
        base[j] = hist[j] ? atomicAdd(&bcur[j], hist[j]) : 0;
    __syncthreads();
    for (int j = t; j < NB; j += 256) hist[j] = base[j];   // reuse as cursor
    __syncthreads();

    for (int be = e0; be < eend_; be += 4096) {
        int s[16], d[16];
#pragma unroll
        for (int u = 0; u < 16; ++u) {
            const int e = be + u * 256 + t;
            if (e < eend_) { s[u] = srcv[e]; d[u] = dstv[e]; }
            else d[u] = -1;
        }
#pragma unroll
        for (int u = 0; u < 16; ++u)
            if (d[u] >= 0) {
                const int b   = d[u] >> 8;
                const int pos = atomicAdd(&hist[b], 1);
                if (pos < CAP) pairs[b * CAP + pos] = (s[u] << 8) | (d[u] & 255);
            }
    }
}

// ---------------------------------------------------------------------------
// Launch 3: FINALIZE (blocks [0,NB)) fused with GEMM L0 (blocks [NB, NB+GB)).
// Finalize hides under gemm0 (~25-40us under ~66us). No intra-launch dep.
// ---------------------------------------------------------------------------
__global__ __launch_bounds__(256) void fin_gemm0_kernel(
    const float* __restrict__ x0, const float* __restrict__ x1,
    const float* __restrict__ x2, const float* __restrict__ x3,
    const __hip_bfloat16* __restrict__ wt, const float* __restrict__ bias,
    __hip_bfloat16* __restrict__ zout, __hip_bfloat16* __restrict__ rout,
    const int* __restrict__ bcur, const int* __restrict__ pairs,
    int* __restrict__ csr, int* __restrict__ beg, int* __restrict__ eend,
    float* __restrict__ inv) {
    __shared__ short lsh[24576];            // gemm: 3x16KB; finalize aliases 3KB
    const int t = threadIdx.x;

    if (blockIdx.x >= NB) {
        gemm_body<256, true>(lsh, blockIdx.x - NB, nullptr, x0, x1, x2, x3,
                             wt, bias, zout, rout);
        return;
    }

    int* cnt = (int*)lsh;
    int* scn = cnt + 256;
    int* cur = scn + 256;
    const int b = blockIdx.x;
    int m = bcur[b];
    if (m > CAP) m = CAP;

    cnt[t] = 0;
    __syncthreads();
    for (int e = t; e < m; e += 256)
        atomicAdd(&cnt[pairs[b * CAP + e] & 255], 1);
    __syncthreads();

    const int v = cnt[t];
    scn[t] = v;
    __syncthreads();
    for (int st = 1; st < 256; st <<= 1) {
        int tv = (t >= st) ? scn[t - st] : 0;
        __syncthreads();
        scn[t] += tv;
        __syncthreads();
    }
    const int myStart = scn[t] - v;          // exclusive scan
    cur[t] = myStart;
    __syncthreads();

    for (int e = t; e < m; e += 256) {
        const int pk  = pairs[b * CAP + e];
        const int pos = atomicAdd(&cur[pk & 255], 1);
        csr[b * CAP + pos] = pk >> 8;
    }

    const int node = b * 256 + t;
    if (node < NN) {
        beg[node]  = b * CAP + myStart;
        eend[node] = b * CAP + myStart + v;
        inv[node]  = 1.0f / fmaxf((float)v, 1.0f);
    }
}

// ---------------------------------------------------------------------------
// Aggregation + combine, r9: h_out = relu(mean_{in-edges}(z[src]) + r).
// 4 NODES PER WAVE, one 16-lane group per node; lane l16 owns features
// [8*l16, 8*l16+8) which stay LANE-LOCAL across all edges -> the cross-lane
// reduce of r8 (16 shfl ops/node) disappears. r8 diagnosis: 100K waves at
// ~9300cy lifetime each (1 node/wave) = wave-overhead-bound, not BW-bound
// (FETCH 194MB @ only 3.07 TB/s, VALU 55%). Now 25K waves, 4 independent
// 4-deep edge-load streams per wave, masked 4-wide tail (clamped idx +
// 0/1 fmaf weights — no serial scalar remainder chain), r-row preloaded
// before the edge loop. LAST: 128-dim proj3 dot -> 4-shfl group reduce.
// ---------------------------------------------------------------------------
template <bool LAST>
__global__ __launch_bounds__(256) void aggregate_kernel(
    const __hip_bfloat16* __restrict__ z, __hip_bfloat16* __restrict__ rio,
    const int* __restrict__ beg, const int* __restrict__ eend,
    const int* __restrict__ csr, const float* __restrict__ inv,
    const float* __restrict__ Wl3, const float* __restrict__ Wr3,
    const float* __restrict__ b3, float* __restrict__ z3,
    float* __restrict__ r3) {
    const int lane = threadIdx.x & 63;
    const int g    = lane >> 4;          // node sub-slot 0..3
    const int l16  = lane & 15;          // feature chunk within the row
    const int i    = ((blockIdx.x * 256 + threadIdx.x) >> 6) * 4 + g;
    if (i >= NN) return;
    const int b0 = beg[i], e0 = eend[i];
    const float iv = inv[i];
    const int  f   = l16 * 8;

    // preload the r-row chunk (independent of the gather loop)
    const bf16x8 rv8 = *(const bf16x8*)&rio[(size_t)i * HH + f];

    float acc[8];
#pragma unroll
    for (int j = 0; j < 8; ++j) acc[j] = 0.f;

    const size_t zoff = (size_t)f;
    int e = b0;
    for (; e + 3 < e0; e += 4) {
        const int s0 = csr[e];
        const int s1 = csr[e + 1];
        const int s2 = csr[e + 2];
        const int s3 = csr[e + 3];
        const bf16x8 z0 = *(const bf16x8*)&z[(size_t)s0 * HH + zoff];
        const bf16x8 z1 = *(const bf16x8*)&z[(size_t)s1 * HH + zoff];
        const bf16x8 z2 = *(const bf16x8*)&z[(size_t)s2 * HH + zoff];
        const bf16x8 z3v = *(const bf16x8*)&z[(size_t)s3 * HH + zoff];
#pragma unroll
        for (int j = 0; j < 8; ++j)
            acc[j] += bf2f(z0[j]) + bf2f(z1[j]) + bf2f(z2[j]) + bf2f(z3v[j]);
    }
    if (e < e0) {                        // masked 4-wide tail (1..3 edges)
        const int s0 = csr[e];
        const int s1 = (e + 1 < e0) ? csr[e + 1] : s0;
        const int s2 = (e + 2 < e0) ? csr[e + 2] : s0;
        const float m1 = (e + 1 < e0) ? 1.f : 0.f;
        const float m2 = (e + 2 < e0) ? 1.f : 0.f;
        const bf16x8 z0 = *(const bf16x8*)&z[(size_t)s0 * HH + zoff];
        const bf16x8 z1 = *(const bf16x8*)&z[(size_t)s1 * HH + zoff];
        const bf16x8 z2 = *(const bf16x8*)&z[(size_t)s2 * HH + zoff];
#pragma unroll
        for (int j = 0; j < 8; ++j) {
            acc[j] += bf2f(z0[j]);
            acc[j] = fmaf(m1, bf2f(z1[j]), acc[j]);
            acc[j] = fmaf(m2, bf2f(z2[j]), acc[j]);
        }
    }

    float ox[8];
    const __hip_bfloat162* rp = (const __hip_bfloat162*)&rv8;
#pragma unroll
    for (int j = 0; j < 4; ++j) {
        ox[2 * j]     = fmaxf(acc[2 * j]     * iv + __bfloat162float(rp[j].x), 0.f);
        ox[2 * j + 1] = fmaxf(acc[2 * j + 1] * iv + __bfloat162float(rp[j].y), 0.f);
    }

    if (!LAST) {
        bf16x8 o;
#pragma unroll
        for (int j = 0; j < 8; ++j) o[j] = f2bf(ox[j]);
        *(bf16x8*)&rio[(size_t)i * HH + f] = o;
    } else {
        const float4 wl0 = *(const float4*)&Wl3[f];
        const float4 wl1 = *(const float4*)&Wl3[f + 4];
        const float4 wr0 = *(const float4*)&Wr3[f];
        const float4 wr1 = *(const float4*)&Wr3[f + 4];
        float al = ox[0] * wl0.x + ox[1] * wl0.y + ox[2] * wl0.z + ox[3] * wl0.w
                 + ox[4] * wl1.x + ox[5] * wl1.y + ox[6] * wl1.z + ox[7] * wl1.w;
        float ar = ox[0] * wr0.x + ox[1] * wr0.y + ox[2] * wr0.z + ox[3] * wr0.w
                 + ox[4] * wr1.x + ox[5] * wr1.y + ox[6] * wr1.z + ox[7] * wr1.w;
#pragma unroll
        for (int m = 8; m; m >>= 1) {     // reduce within the 16-lane group
            al += __shfl_xor(al, m, 64);
            ar += __shfl_xor(ar, m, 64);
        }
        if (l16 == 0) {
            z3[i] = al;
            r3[i] = ar + b3[0];
        }
    }
}

// Final: 4 nodes per wave, 16 lanes each; sigmoid + per-block partial sums
__global__ __launch_bounds__(256) void final_kernel(
    const float* __restrict__ z3, const float* __restrict__ r3,
    const int* __restrict__ beg, const int* __restrict__ eend,
    const int* __restrict__ csr, const float* __restrict__ inv,
    float* __restrict__ out, float* __restrict__ partial) {
    __shared__ float red[4];
    const int wv   = (blockIdx.x * 256 + threadIdx.x) >> 6;  // global wave id
    const int lane = threadIdx.x & 63;
    const int sub  = lane >> 4;          // node sub-slot 0..3
    const int l16  = lane & 15;
    const int w    = threadIdx.x >> 6;
    const int i    = wv * 4 + sub;
    float s = 0.f;
    if (i < NN) {
        const int b0 = beg[i], e0 = eend[i];
        float a = 0.f;
        for (int e = b0 + l16; e < e0; e += 16) a += z3[csr[e]];
        a += __shfl_xor(a, 1, 64);
        a += __shfl_xor(a, 2, 64);
        a += __shfl_xor(a, 4, 64);
        a += __shfl_xor(a, 8, 64);
        const float pre = a * inv[i] + r3[i];
        const float sg  = 1.f / (1.f + __expf(-pre));
        if (l16 == 0) { out[i] = sg; s = sg; }
    }
    s += __shfl_xor(s, 16, 64);
    s += __shfl_xor(s, 32, 64);
    if (lane == 0) red[w] = s;
    __syncthreads();
    if (threadIdx.x == 0)
        partial[blockIdx.x] = red[0] + red[1] + red[2] + red[3];
}

__global__ __launch_bounds__(256) void mean_kernel(const float* __restrict__ partial,
                                                   int nb, float* __restrict__ out) {
    __shared__ float lds[256];
    float s = 0.f;
    for (int i = threadIdx.x; i < nb; i += 256) s += partial[i];
    lds[threadIdx.x] = s;
    __syncthreads();
    for (int st = 128; st; st >>= 1) {
        if (threadIdx.x < st) lds[threadIdx.x] += lds[threadIdx.x + st];
        __syncthreads();
    }
    if (threadIdx.x == 0) out[NN] = lds[0] / (float)NN;
}

// ---------------------------------------------------------------------------
extern "C" void kernel_launch(void* const* d_in, const int* in_sizes, int n_in,
                              void* d_out, int out_size, void* d_ws, size_t ws_size,
                              hipStream_t stream) {
    const float* x    = (const float*)d_in[0];
    const float* diff = (const float*)d_in[1];
    const float* rec  = (const float*)d_in[2];
    const float* hid  = (const float*)d_in[3];
    const int* edge   = (const int*)d_in[4];
    const int* esrc = edge;        // row 0
    const int* edst = edge + EE;   // row 1
    const float* Wl0 = (const float*)d_in[5];
    const float* Wr0 = (const float*)d_in[6];
    const float* b0  = (const float*)d_in[7];
    const float* Wl1 = (const float*)d_in[8];
    const float* Wr1 = (const float*)d_in[9];
    const float* b1  = (const float*)d_in[10];
    const float* Wl2 = (const float*)d_in[11];
    const float* Wr2 = (const float*)d_in[12];
    const float* b2  = (const float*)d_in[13];
    const float* Wl3 = (const float*)d_in[14];
    const float* Wr3 = (const float*)d_in[15];
    const float* b3  = (const float*)d_in[16];
    float* out = (float*)d_out;

    // workspace carve-out (256B aligned) — total ~70 MB
    char* w = (char*)d_ws;
    auto alloc = [&](size_t bytes) -> void* {
        void* p = (void*)w;
        w += (bytes + 255) & ~(size_t)255;
        return p;
    };
    __hip_bfloat16* bufA = (__hip_bfloat16*)alloc((size_t)NN * HH * 2);  // 25.6 MB
    __hip_bfloat16* bufB = (__hip_bfloat16*)alloc((size_t)NN * HH * 2);  // 25.6 MB
    __hip_bfloat16* WT0  = (__hip_bfloat16*)alloc((size_t)256 * 256 * 2);
    __hip_bfloat16* WT1  = (__hip_bfloat16*)alloc((size_t)256 * 128 * 2);
    __hip_bfloat16* WT2  = (__hip_bfloat16*)alloc((size_t)256 * 128 * 2);
    int*   pairs   = (int*)alloc((size_t)NB * CAP * 4);                  // 8.0 MB
    int*   csr     = (int*)alloc((size_t)NB * CAP * 4);                  // 8.0 MB
    int*   bcur    = (int*)alloc((size_t)512 * 4);
    int*   beg     = (int*)alloc((size_t)NN * 4);
    int*   eend    = (int*)alloc((size_t)NN * 4);
    float* inv     = (float*)alloc((size_t)NN * 4);
    float* z3      = (float*)alloc((size_t)NN * 4);
    float* r3      = (float*)alloc((size_t)NN * 4);
    float* partial = (float*)alloc((size_t)25000 * 4);

    // Launch 1: weight prep + zero cursors
    prep_kernel<<<129, 1024, 0, stream>>>(Wl0, Wr0, Wl1, Wr1, Wl2, Wr2,
                                          WT0, WT1, WT2, bcur);

    // Launch 2: edge scatter (standalone)
    scatter_kernel<<<SB, 256, 0, stream>>>(esrc, edst, bcur, pairs);

    // Launch 3: finalize CSR (blocks 0..NB) fused with gemm L0 (z->A, r->B)
    fin_gemm0_kernel<<<NB + GB, 256, 0, stream>>>(
        x, diff, rec, hid, WT0, b0, bufA, bufB,
        bcur, pairs, csr, beg, eend, inv);

    // agg L0: h1 -> B (over r)
    aggregate_kernel<false><<<AB, 256, 0, stream>>>(bufA, bufB, beg, eend, csr, inv,
                                                    nullptr, nullptr, nullptr,
                                                    nullptr, nullptr);

    // L1: h in B; z in-place -> B, r -> A; agg: h2 -> A
    gemm_kernel<128><<<GB, 256, 0, stream>>>(bufB, WT1, b1, bufB, bufA);
    aggregate_kernel<false><<<AB, 256, 0, stream>>>(bufB, bufA, beg, eend, csr, inv,
                                                    nullptr, nullptr, nullptr,
                                                    nullptr, nullptr);

    // L2: h in A; z in-place -> A, r -> B; agg(LAST): fused proj3 -> z3, r3
    gemm_kernel<128><<<GB, 256, 0, stream>>>(bufA, WT2, b2, bufA, bufB);
    aggregate_kernel<true><<<AB, 256, 0, stream>>>(bufA, bufB, beg, eend, csr, inv,
                                                   Wl3, Wr3, b3, z3, r3);

    // final: 16 nodes/block, sigmoid + partial sums; then mean
    final_kernel<<<FB, 256, 0, stream>>>(z3, r3, beg, eend, csr, inv, out, partial);
    mean_kernel<<<1, 256, 0, stream>>>(partial, FB, out);
}